// Round 1
// baseline (581.883 us; speedup 1.0000x reference)
//
#include <hip/hip_runtime.h>
#include <cstdint>
#include <cstddef>

#define NB 32
#define NG 30
#define NA 8400
#define NC 80

struct Params {
  const float* f8; const float* f16; const float* f32; const float* lab;
  float* bbox;    // [NB*NA*4] decoded cx,cy,w,h
  float* objlog;  // [NB*NA]   raw obj logit
  float* base_;   // [NB*NA]   -sum_c log(1-p_c+eps)
  int*   aok;     // [NB*NA]   anchor_ok
  float* thrc;    // [NB*NG]   dyn_k-th smallest cost
  int*   thri;    // [NB*NG]   its anchor index (stable-sort tiebreak)
  float* acc;     // [4] loss_iou, loss_obj, loss_cls, num_fg
};

__device__ __forceinline__ float sigm(float x) { return 1.0f / (1.0f + expf(-x)); }

__device__ __forceinline__ void anchor_geom(int a, int& x, int& y, int& W, int& hw,
                                            float& stride, int& lvl) {
  if (a < 6400)      { W = 80; hw = 6400; stride = 8.f;  lvl = 0; int i = a;        y = i / 80; x = i - y * 80; }
  else if (a < 8000) { W = 40; hw = 1600; stride = 16.f; lvl = 1; int i = a - 6400; y = i / 40; x = i - y * 40; }
  else               { W = 20; hw = 400;  stride = 32.f; lvl = 2; int i = a - 8000; y = i / 20; x = i - y * 20; }
}

// Cost + (anchor_ok-zeroed) IoU for one (b, g, a).
// __noinline__ so K3 and K4 run bit-identical code (threshold equality test).
__device__ __attribute__((noinline)) float2 cost_iou(Params p, int b, int g, int a) {
  int x, y, W, hw, lvl; float stride;
  anchor_geom(a, x, y, W, hw, stride, lvl);
  const float* f = (lvl == 0) ? p.f8 : (lvl == 1) ? p.f16 : p.f32;
  const float* fb = f + (size_t)b * 85 * hw;
  int idx = y * W + x;

  const float* gt = p.lab + ((size_t)b * NG + g) * 5;
  float gx = gt[0], gy = gt[1], gw = gt[2], gh = gt[3];
  int cg = (int)gt[4];

  const float* bb = p.bbox + ((size_t)(b * NA + a)) * 4;
  float px = bb[0], py = bb[1], pw = bb[2], ph = bb[3];
  int aok = p.aok[b * NA + a];

  // pairwise IoU (gt vs decoded pred)
  float tlx = fmaxf(gx - gw * 0.5f, px - pw * 0.5f);
  float tly = fmaxf(gy - gh * 0.5f, py - ph * 0.5f);
  float brx = fminf(gx + gw * 0.5f, px + pw * 0.5f);
  float bry = fminf(gy + gh * 0.5f, py + ph * 0.5f);
  float inter = ((tlx < brx) && (tly < bry)) ? (brx - tlx) * (bry - tly) : 0.0f;
  float iou = inter / (gw * gh + pw * ph - inter + 1e-16f);
  iou = aok ? iou : 0.0f;
  float iou_cost = -logf(iou + 1e-8f);

  // geometry gates
  float xc = ((float)x + 0.5f) * stride;
  float yc = ((float)y + 0.5f) * stride;
  bool inb = (xc > gx - 0.5f * gw) && (xc < gx + 0.5f * gw) &&
             (yc > gy - 0.5f * gh) && (yc < gy + 0.5f * gh);
  float r = 2.5f * stride;
  bool inc = (xc > gx - r) && (xc < gx + r) && (yc > gy - r) && (yc < gy + r);
  bool in_both = inb && inc;

  // cls cost for this gt's class
  float xl = fb[(size_t)(5 + cg) * hw + idx];
  float po = sigm(p.objlog[b * NA + a]);
  float pc = sigm(xl);
  float pr = sqrtf(pc * po);
  float logp = logf(pr + 1e-8f);
  float log1mp = logf(1.0f - pr + 1e-8f);
  float cls_cost = p.base_[b * NA + a] - (logp - log1mp);

  float cost = cls_cost + 3.0f * iou_cost;
  cost = cost + (in_both ? 0.0f : 100000.0f);
  cost = cost + (aok ? 0.0f : 1000000000.0f);
  return make_float2(cost, iou);
}

// K1: decode bbox/obj, per-anchor cls "base" term, anchor_ok
__global__ __launch_bounds__(256) void k_decode(Params p) {
  __shared__ float sgt[NG * 5];
  int b = blockIdx.y;
  int tid = threadIdx.x;
  if (tid < NG * 5) sgt[tid] = p.lab[(size_t)b * NG * 5 + tid];
  __syncthreads();
  int a = blockIdx.x * 256 + tid;
  if (a >= NA) return;

  int x, y, W, hw, lvl; float stride;
  anchor_geom(a, x, y, W, hw, stride, lvl);
  const float* f = (lvl == 0) ? p.f8 : (lvl == 1) ? p.f16 : p.f32;
  const float* fb = f + (size_t)b * 85 * hw;
  int idx = y * W + x;

  float tx = fb[idx];
  float ty = fb[hw + idx];
  float tw = fb[2 * hw + idx];
  float th = fb[3 * hw + idx];
  float ob = fb[4 * hw + idx];

  float cx = (tx + (float)x) * stride;
  float cy = (ty + (float)y) * stride;
  float w  = expf(tw) * stride;
  float h  = expf(th) * stride;

  float* bb = p.bbox + ((size_t)(b * NA + a)) * 4;
  bb[0] = cx; bb[1] = cy; bb[2] = w; bb[3] = h;
  p.objlog[b * NA + a] = ob;

  float po = sigm(ob);
  float bs = 0.0f;
  for (int c = 0; c < NC; c++) {
    float xl = fb[(size_t)(5 + c) * hw + idx];
    float pc = sigm(xl);
    float pr = sqrtf(pc * po);
    bs -= logf(1.0f - pr + 1e-8f);
  }
  p.base_[b * NA + a] = bs;

  float xc = ((float)x + 0.5f) * stride;
  float yc = ((float)y + 0.5f) * stride;
  float r = 2.5f * stride;
  int ok = 0;
  for (int g = 0; g < NG; g++) {
    float gx = sgt[g * 5], gy = sgt[g * 5 + 1], gw = sgt[g * 5 + 2], gh = sgt[g * 5 + 3];
    bool inb = (xc > gx - 0.5f * gw) && (xc < gx + 0.5f * gw) &&
               (yc > gy - 0.5f * gh) && (yc < gy + 0.5f * gh);
    bool inc = (xc > gx - r) && (xc < gx + r) && (yc > gy - r) && (yc < gy + r);
    if (inb || inc) { ok = 1; break; }
  }
  p.aok[b * NA + a] = ok;
}

// K3: one block per (b,g). Top-10 IoUs -> dyn_k; dyn_k-th smallest (cost,idx) -> threshold.
__global__ __launch_bounds__(256) void k_topk(Params p) {
  __shared__ float sv[256];
  __shared__ int   si[256];
  int bg = blockIdx.x;
  int b = bg / NG, g = bg % NG;
  int tid = threadIdx.x;

  float v[10];                 // local top-10 ious, descending
  float cv[10]; int ci[10];    // local 10 smallest (cost, idx), ascending
#pragma unroll
  for (int j = 0; j < 10; j++) { v[j] = -1.0f; cv[j] = 3.4e38f; ci[j] = 0x7FFFFFFF; }

  for (int a = tid; a < NA; a += 256) {
    float2 cio = cost_iou(p, b, g, a);
    float iou = cio.y, c = cio.x;
    if (iou > v[9]) {
      int j = 9;
      while (j > 0 && iou > v[j - 1]) { v[j] = v[j - 1]; j--; }
      v[j] = iou;
    }
    if (c < cv[9] || (c == cv[9] && a < ci[9])) {
      int j = 9;
      while (j > 0 && (c < cv[j - 1] || (c == cv[j - 1] && a < ci[j - 1]))) {
        cv[j] = cv[j - 1]; ci[j] = ci[j - 1]; j--;
      }
      cv[j] = c; ci[j] = a;
    }
  }

  // merge top-10 ious (pop global max 10x), sum in descending order
  float sum = 0.0f; int ptr = 0;
  for (int it = 0; it < 10; it++) {
    sv[tid] = (ptr < 10) ? v[ptr] : -1e30f;
    si[tid] = tid;
    __syncthreads();
    for (int s = 128; s > 0; s >>= 1) {
      if (tid < s) {
        if (sv[tid + s] > sv[tid]) { sv[tid] = sv[tid + s]; si[tid] = si[tid + s]; }
      }
      __syncthreads();
    }
    float win = sv[0]; int wt = si[0];
    __syncthreads();
    if (tid == wt) ptr++;
    sum += win;
  }
  int dynk = (int)sum;
  if (dynk < 1) dynk = 1;

  // pop global lexicographic min dynk times; last popped = threshold pair
  ptr = 0;
  float thc = 0.0f; int thi = 0;
  for (int it = 0; it < dynk; it++) {
    sv[tid] = (ptr < 10) ? cv[ptr] : 3.4e38f;
    si[tid] = (ptr < 10) ? ci[ptr] : 0x7FFFFFFF;
    __syncthreads();
    for (int s = 128; s > 0; s >>= 1) {
      if (tid < s) {
        float c2 = sv[tid + s]; int i2 = si[tid + s];
        if (c2 < sv[tid] || (c2 == sv[tid] && i2 < si[tid])) { sv[tid] = c2; si[tid] = i2; }
      }
      __syncthreads();
    }
    thc = sv[0]; thi = si[0];
    __syncthreads();
    if (ptr < 10 && ci[ptr] == thi) ptr++;  // anchor idx is unique -> exactly one owner advances
  }
  if (tid == 0) { p.thrc[bg] = thc; p.thri[bg] = thi; }
}

__device__ __forceinline__ float block_sum(float val, volatile float* sw) {
#pragma unroll
  for (int off = 32; off > 0; off >>= 1) val += __shfl_down(val, off, 64);
  int lane = threadIdx.x & 63, wv = threadIdx.x >> 6;
  __syncthreads();
  if (lane == 0) sw[wv] = val;
  __syncthreads();
  float r = 0.0f;
  if (threadIdx.x == 0) r = sw[0] + sw[1] + sw[2] + sw[3];
  return r;
}

// K4: per (b,a) matching + loss contributions
__global__ __launch_bounds__(256) void k_match(Params p) {
  __shared__ float sth[NG];
  __shared__ int   sti[NG];
  __shared__ float sred[4];
  int b = blockIdx.y;
  int tid = threadIdx.x;
  if (tid < NG) { sth[tid] = p.thrc[b * NG + tid]; sti[tid] = p.thri[b * NG + tid]; }
  __syncthreads();
  int a = blockIdx.x * 256 + tid;

  float l_iou = 0.0f, l_obj = 0.0f, l_cls = 0.0f, l_nfg = 0.0f;
  if (a < NA) {
    int aok = p.aok[b * NA + a];
    unsigned mask = 0; int am = 0;
    float minc = 3.4e38f; int ming = 0;
    for (int g = 0; g < NG; g++) {
      float c = cost_iou(p, b, g, a).x;
      if (c < minc) { minc = c; ming = g; }
      bool m = aok && (c < sth[g] || (c == sth[g] && a <= sti[g]));
      if (m) { mask |= (1u << g); am++; }
    }
    if (am > 1) mask = (1u << ming);
    bool fg = (mask != 0u);

    float ol = p.objlog[b * NA + a];
    float tfg = fg ? 1.0f : 0.0f;
    l_obj = fmaxf(ol, 0.0f) - ol * tfg + log1pf(expf(-fabsf(ol)));

    if (fg) {
      l_nfg = 1.0f;
      int mg = __ffs(mask) - 1;
      float pred_iou = 0.0f;
      unsigned mm = mask;
      while (mm) { int g = __ffs(mm) - 1; mm &= mm - 1u; pred_iou += cost_iou(p, b, g, a).y; }

      const float* gt = p.lab + ((size_t)b * NG + mg) * 5;
      float gx = gt[0], gy = gt[1], gw = gt[2], gh = gt[3];
      int cg = (int)gt[4];
      const float* bb = p.bbox + ((size_t)(b * NA + a)) * 4;
      float px = bb[0], py = bb[1], pw = bb[2], ph = bb[3];

      float tlx = fmaxf(px - pw * 0.5f, gx - gw * 0.5f);
      float tly = fmaxf(py - ph * 0.5f, gy - gh * 0.5f);
      float brx = fminf(px + pw * 0.5f, gx + gw * 0.5f);
      float bry = fminf(py + ph * 0.5f, gy + gh * 0.5f);
      float ap = pw * ph, ag = gw * gh;
      float ai = ((tlx < brx) && (tly < bry)) ? (brx - tlx) * (bry - tly) : 0.0f;
      float iouE = ai / (ap + ag - ai + 1e-16f);
      l_iou = 1.0f - iouE * iouE;

      int x, y, W, hw, lvl; float stride;
      anchor_geom(a, x, y, W, hw, stride, lvl);
      const float* f = (lvl == 0) ? p.f8 : (lvl == 1) ? p.f16 : p.f32;
      const float* fb = f + (size_t)b * 85 * hw;
      int idx = y * W + x;
      for (int c = 0; c < NC; c++) {
        float xl = fb[(size_t)(5 + c) * hw + idx];
        float t = (c == cg) ? pred_iou : 0.0f;
        l_cls += fmaxf(xl, 0.0f) - xl * t + log1pf(expf(-fabsf(xl)));
      }
    }
  }

  float s0 = block_sum(l_iou, sred);
  float s1 = block_sum(l_obj, sred);
  float s2 = block_sum(l_cls, sred);
  float s3 = block_sum(l_nfg, sred);
  if (tid == 0) {
    atomicAdd(&p.acc[0], s0);
    atomicAdd(&p.acc[1], s1);
    atomicAdd(&p.acc[2], s2);
    atomicAdd(&p.acc[3], s3);
  }
}

__global__ void k_final(Params p, float* out) {
  float li = p.acc[0], lo = p.acc[1], lc = p.acc[2], nf = p.acc[3];
  float nfg = fmaxf(nf, 1.0f);
  out[0] = (5.0f * li + 0.1f * lo + lc) / nfg;
}

extern "C" void kernel_launch(void* const* d_in, const int* in_sizes, int n_in,
                              void* d_out, int out_size, void* d_ws, size_t ws_size,
                              hipStream_t stream) {
  Params p;
  p.f8  = (const float*)d_in[0];
  p.f16 = (const float*)d_in[1];
  p.f32 = (const float*)d_in[2];
  p.lab = (const float*)d_in[3];

  float* w = (float*)d_ws;
  p.bbox   = w;          w += (size_t)NB * NA * 4;
  p.objlog = w;          w += (size_t)NB * NA;
  p.base_  = w;          w += (size_t)NB * NA;
  p.aok    = (int*)w;    w += (size_t)NB * NA;
  p.thrc   = w;          w += (size_t)NB * NG;
  p.thri   = (int*)w;    w += (size_t)NB * NG;
  p.acc    = w;          w += 4;

  hipMemsetAsync(p.acc, 0, 4 * sizeof(float), stream);

  dim3 gd((NA + 255) / 256, NB);
  k_decode<<<gd, 256, 0, stream>>>(p);
  k_topk<<<NB * NG, 256, 0, stream>>>(p);
  k_match<<<gd, 256, 0, stream>>>(p);
  k_final<<<1, 1, 0, stream>>>(p, (float*)d_out);
}

// Round 2
// 372.460 us; speedup vs baseline: 1.5623x; 1.5623x over previous
//
#include <hip/hip_runtime.h>
#include <cstdint>
#include <cstddef>

#define NB 32
#define NG 30
#define NA 8400
#define NC 80

struct Params {
  const float* f8; const float* f16; const float* f32; const float* lab;
  float* bbox;    // [NB*NA*4] decoded cx,cy,w,h
  float* objlog;  // [NB*NA]   raw obj logit
  float* base_;   // [NB*NA]   -sum_c log(1-p_c+eps)
  int*   aok;     // [NB*NA]   anchor_ok
  float* cost;    // [NB*NG*NA] full cost matrix (computed once in K3)
  float* thrc;    // [NB*NG]   dyn_k-th smallest cost
  int*   thri;    // [NB*NG]   its anchor index (stable-sort tiebreak)
  float* acc;     // [4] loss_iou, loss_obj, loss_cls, num_fg
};

__device__ __forceinline__ float sigm(float x) { return 1.0f / (1.0f + expf(-x)); }

__device__ __forceinline__ void anchor_geom(int a, int& x, int& y, int& W, int& hw,
                                            float& stride, int& lvl) {
  if (a < 6400)      { W = 80; hw = 6400; stride = 8.f;  lvl = 0; int i = a;        y = i / 80; x = i - y * 80; }
  else if (a < 8000) { W = 40; hw = 1600; stride = 16.f; lvl = 1; int i = a - 6400; y = i / 40; x = i - y * 40; }
  else               { W = 20; hw = 400;  stride = 32.f; lvl = 2; int i = a - 8000; y = i / 20; x = i - y * 20; }
}

// K1: decode bbox/obj, per-anchor cls "base" term, anchor_ok
__global__ __launch_bounds__(256) void k_decode(Params p) {
  __shared__ float sgt[NG * 5];
  int b = blockIdx.y;
  int tid = threadIdx.x;
  if (tid < NG * 5) sgt[tid] = p.lab[(size_t)b * NG * 5 + tid];
  __syncthreads();
  int a = blockIdx.x * 256 + tid;
  if (a >= NA) return;

  int x, y, W, hw, lvl; float stride;
  anchor_geom(a, x, y, W, hw, stride, lvl);
  const float* f = (lvl == 0) ? p.f8 : (lvl == 1) ? p.f16 : p.f32;
  const float* fb = f + (size_t)b * 85 * hw;
  int idx = y * W + x;

  float tx = fb[idx];
  float ty = fb[hw + idx];
  float tw = fb[2 * hw + idx];
  float th = fb[3 * hw + idx];
  float ob = fb[4 * hw + idx];

  float cx = (tx + (float)x) * stride;
  float cy = (ty + (float)y) * stride;
  float w  = expf(tw) * stride;
  float h  = expf(th) * stride;

  float* bb = p.bbox + ((size_t)(b * NA + a)) * 4;
  bb[0] = cx; bb[1] = cy; bb[2] = w; bb[3] = h;
  p.objlog[b * NA + a] = ob;

  float po = sigm(ob);
  float bs = 0.0f;
  for (int c = 0; c < NC; c++) {
    float xl = fb[(size_t)(5 + c) * hw + idx];
    float pc = sigm(xl);
    float pr = sqrtf(pc * po);
    bs -= logf(1.0f - pr + 1e-8f);
  }
  p.base_[b * NA + a] = bs;

  float xc = ((float)x + 0.5f) * stride;
  float yc = ((float)y + 0.5f) * stride;
  float r = 2.5f * stride;
  int ok = 0;
  for (int g = 0; g < NG; g++) {
    float gx = sgt[g * 5], gy = sgt[g * 5 + 1], gw = sgt[g * 5 + 2], gh = sgt[g * 5 + 3];
    bool inb = (xc > gx - 0.5f * gw) && (xc < gx + 0.5f * gw) &&
               (yc > gy - 0.5f * gh) && (yc < gy + 0.5f * gh);
    bool inc = (xc > gx - r) && (xc < gx + r) && (yc > gy - r) && (yc < gy + r);
    if (inb || inc) { ok = 1; break; }
  }
  p.aok[b * NA + a] = ok;
}

// K3: one block per (b,g). Computes cost (stored to p.cost) + iou inline.
// Top-10 IoUs -> dyn_k; dyn_k-th smallest (cost,idx) -> threshold.
__global__ __launch_bounds__(256) void k_topk(Params p) {
  __shared__ float sv[256];
  __shared__ int   si[256];
  int bg = blockIdx.x;
  int b = bg / NG, g = bg % NG;
  int tid = threadIdx.x;

  const float* gt = p.lab + ((size_t)b * NG + g) * 5;
  float gx = gt[0], gy = gt[1], gw = gt[2], gh = gt[3];
  int cg = (int)gt[4];
  float area_g = gw * gh;
  float glx = gx - 0.5f * gw, grx = gx + 0.5f * gw;
  float gty = gy - 0.5f * gh, gby = gy + 0.5f * gh;

  float v[10];                 // local top-10 ious, descending
  float cv[10]; int ci[10];    // local 10 smallest (cost, idx), ascending
#pragma unroll
  for (int j = 0; j < 10; j++) { v[j] = -1.0f; cv[j] = 3.4e38f; ci[j] = 0x7FFFFFFF; }

  float* crow = p.cost + (size_t)bg * NA;

  for (int a = tid; a < NA; a += 256) {
    int x, y, W, hw, lvl; float stride;
    anchor_geom(a, x, y, W, hw, stride, lvl);
    const float* f = (lvl == 0) ? p.f8 : (lvl == 1) ? p.f16 : p.f32;
    const float* fb = f + (size_t)b * 85 * hw;
    int idx = y * W + x;

    float4 bb = *(const float4*)(p.bbox + ((size_t)(b * NA + a)) * 4);
    float px = bb.x, py = bb.y, pw = bb.z, ph = bb.w;
    int aok = p.aok[b * NA + a];

    // pairwise IoU (gt vs decoded pred)
    float tlx = fmaxf(glx, px - pw * 0.5f);
    float tly = fmaxf(gty, py - ph * 0.5f);
    float brx = fminf(grx, px + pw * 0.5f);
    float bry = fminf(gby, py + ph * 0.5f);
    float inter = ((tlx < brx) && (tly < bry)) ? (brx - tlx) * (bry - tly) : 0.0f;
    float iou = inter / (area_g + pw * ph - inter + 1e-16f);
    iou = aok ? iou : 0.0f;
    float iou_cost = -logf(iou + 1e-8f);

    // geometry gates
    float xc = ((float)x + 0.5f) * stride;
    float yc = ((float)y + 0.5f) * stride;
    bool inb = (xc > glx) && (xc < grx) && (yc > gty) && (yc < gby);
    float r = 2.5f * stride;
    bool inc = (xc > gx - r) && (xc < gx + r) && (yc > gy - r) && (yc < gy + r);
    bool in_both = inb && inc;

    // cls cost for this gt's class
    float xl = fb[(size_t)(5 + cg) * hw + idx];
    float po = sigm(p.objlog[b * NA + a]);
    float pc = sigm(xl);
    float pr = sqrtf(pc * po);
    float logp = logf(pr + 1e-8f);
    float log1mp = logf(1.0f - pr + 1e-8f);
    float cls_cost = p.base_[b * NA + a] - (logp - log1mp);

    float c = cls_cost + 3.0f * iou_cost;
    c = c + (in_both ? 0.0f : 100000.0f);
    c = c + (aok ? 0.0f : 1000000000.0f);
    crow[a] = c;

    if (iou > v[9]) {
      int j = 9;
      while (j > 0 && iou > v[j - 1]) { v[j] = v[j - 1]; j--; }
      v[j] = iou;
    }
    if (c < cv[9] || (c == cv[9] && a < ci[9])) {
      int j = 9;
      while (j > 0 && (c < cv[j - 1] || (c == cv[j - 1] && a < ci[j - 1]))) {
        cv[j] = cv[j - 1]; ci[j] = ci[j - 1]; j--;
      }
      cv[j] = c; ci[j] = a;
    }
  }

  // merge top-10 ious (pop global max 10x), sum in descending order
  float sum = 0.0f; int ptr = 0;
  for (int it = 0; it < 10; it++) {
    sv[tid] = (ptr < 10) ? v[ptr] : -1e30f;
    si[tid] = tid;
    __syncthreads();
    for (int s = 128; s > 0; s >>= 1) {
      if (tid < s) {
        if (sv[tid + s] > sv[tid]) { sv[tid] = sv[tid + s]; si[tid] = si[tid + s]; }
      }
      __syncthreads();
    }
    float win = sv[0]; int wt = si[0];
    __syncthreads();
    if (tid == wt) ptr++;
    sum += win;
  }
  int dynk = (int)sum;
  if (dynk < 1) dynk = 1;

  // pop global lexicographic min dynk times; last popped = threshold pair
  ptr = 0;
  float thc = 0.0f; int thi = 0;
  for (int it = 0; it < dynk; it++) {
    sv[tid] = (ptr < 10) ? cv[ptr] : 3.4e38f;
    si[tid] = (ptr < 10) ? ci[ptr] : 0x7FFFFFFF;
    __syncthreads();
    for (int s = 128; s > 0; s >>= 1) {
      if (tid < s) {
        float c2 = sv[tid + s]; int i2 = si[tid + s];
        if (c2 < sv[tid] || (c2 == sv[tid] && i2 < si[tid])) { sv[tid] = c2; si[tid] = i2; }
      }
      __syncthreads();
    }
    thc = sv[0]; thi = si[0];
    __syncthreads();
    if (ptr < 10 && ci[ptr] == thi) ptr++;  // anchor idx is unique -> exactly one owner advances
  }
  if (tid == 0) { p.thrc[bg] = thc; p.thri[bg] = thi; }
}

__device__ __forceinline__ float block_sum(float val, volatile float* sw) {
#pragma unroll
  for (int off = 32; off > 0; off >>= 1) val += __shfl_down(val, off, 64);
  int lane = threadIdx.x & 63, wv = threadIdx.x >> 6;
  __syncthreads();
  if (lane == 0) sw[wv] = val;
  __syncthreads();
  float r = 0.0f;
  if (threadIdx.x == 0) r = sw[0] + sw[1] + sw[2] + sw[3];
  return r;
}

// K4: per (b,a) matching (reads stored cost matrix) + loss contributions
__global__ __launch_bounds__(256) void k_match(Params p) {
  __shared__ float sth[NG];
  __shared__ int   sti[NG];
  __shared__ float sred[4];
  int b = blockIdx.y;
  int tid = threadIdx.x;
  if (tid < NG) { sth[tid] = p.thrc[b * NG + tid]; sti[tid] = p.thri[b * NG + tid]; }
  __syncthreads();
  int a = blockIdx.x * 256 + tid;

  float l_iou = 0.0f, l_obj = 0.0f, l_cls = 0.0f, l_nfg = 0.0f;
  if (a < NA) {
    int aok = p.aok[b * NA + a];
    const float* ccol = p.cost + (size_t)b * NG * NA + a;
    unsigned mask = 0; int am = 0;
    float minc = 3.4e38f; int ming = 0;
    for (int g = 0; g < NG; g++) {
      float c = ccol[(size_t)g * NA];
      if (c < minc) { minc = c; ming = g; }
      bool m = aok && (c < sth[g] || (c == sth[g] && a <= sti[g]));
      if (m) { mask |= (1u << g); am++; }
    }
    if (am > 1) mask = (1u << ming);
    bool fg = (mask != 0u);

    float ol = p.objlog[b * NA + a];
    float tfg = fg ? 1.0f : 0.0f;
    l_obj = fmaxf(ol, 0.0f) - ol * tfg + log1pf(expf(-fabsf(ol)));

    if (fg) {
      l_nfg = 1.0f;
      int mg = __ffs(mask) - 1;

      float4 bbv = *(const float4*)(p.bbox + ((size_t)(b * NA + a)) * 4);
      float px = bbv.x, py = bbv.y, pw = bbv.z, ph = bbv.w;

      // pred_iou = sum over matched g of pairwise IoU (all matched g have aok=1)
      float pred_iou = 0.0f;
      unsigned mm = mask;
      while (mm) {
        int g = __ffs(mm) - 1; mm &= mm - 1u;
        const float* gtg = p.lab + ((size_t)b * NG + g) * 5;
        float gx = gtg[0], gy = gtg[1], gw = gtg[2], gh = gtg[3];
        float tlx = fmaxf(gx - gw * 0.5f, px - pw * 0.5f);
        float tly = fmaxf(gy - gh * 0.5f, py - ph * 0.5f);
        float brx = fminf(gx + gw * 0.5f, px + pw * 0.5f);
        float bry = fminf(gy + gh * 0.5f, py + ph * 0.5f);
        float inter = ((tlx < brx) && (tly < bry)) ? (brx - tlx) * (bry - tly) : 0.0f;
        pred_iou += inter / (gw * gh + pw * ph - inter + 1e-16f);
      }

      const float* gt = p.lab + ((size_t)b * NG + mg) * 5;
      float gx = gt[0], gy = gt[1], gw = gt[2], gh = gt[3];
      int cg = (int)gt[4];

      float tlx = fmaxf(px - pw * 0.5f, gx - gw * 0.5f);
      float tly = fmaxf(py - ph * 0.5f, gy - gh * 0.5f);
      float brx = fminf(px + pw * 0.5f, gx + gw * 0.5f);
      float bry = fminf(py + ph * 0.5f, gy + gh * 0.5f);
      float ap = pw * ph, ag = gw * gh;
      float ai = ((tlx < brx) && (tly < bry)) ? (brx - tlx) * (bry - tly) : 0.0f;
      float iouE = ai / (ap + ag - ai + 1e-16f);
      l_iou = 1.0f - iouE * iouE;

      int x, y, W, hw, lvl; float stride;
      anchor_geom(a, x, y, W, hw, stride, lvl);
      const float* f = (lvl == 0) ? p.f8 : (lvl == 1) ? p.f16 : p.f32;
      const float* fb = f + (size_t)b * 85 * hw;
      int idx = y * W + x;
      for (int c = 0; c < NC; c++) {
        float xl = fb[(size_t)(5 + c) * hw + idx];
        float t = (c == cg) ? pred_iou : 0.0f;
        l_cls += fmaxf(xl, 0.0f) - xl * t + log1pf(expf(-fabsf(xl)));
      }
    }
  }

  float s0 = block_sum(l_iou, sred);
  float s1 = block_sum(l_obj, sred);
  float s2 = block_sum(l_cls, sred);
  float s3 = block_sum(l_nfg, sred);
  if (tid == 0) {
    atomicAdd(&p.acc[0], s0);
    atomicAdd(&p.acc[1], s1);
    atomicAdd(&p.acc[2], s2);
    atomicAdd(&p.acc[3], s3);
  }
}

__global__ void k_final(Params p, float* out) {
  float li = p.acc[0], lo = p.acc[1], lc = p.acc[2], nf = p.acc[3];
  float nfg = fmaxf(nf, 1.0f);
  out[0] = (5.0f * li + 0.1f * lo + lc) / nfg;
}

extern "C" void kernel_launch(void* const* d_in, const int* in_sizes, int n_in,
                              void* d_out, int out_size, void* d_ws, size_t ws_size,
                              hipStream_t stream) {
  Params p;
  p.f8  = (const float*)d_in[0];
  p.f16 = (const float*)d_in[1];
  p.f32 = (const float*)d_in[2];
  p.lab = (const float*)d_in[3];

  float* w = (float*)d_ws;
  p.bbox   = w;          w += (size_t)NB * NA * 4;
  p.objlog = w;          w += (size_t)NB * NA;
  p.base_  = w;          w += (size_t)NB * NA;
  p.aok    = (int*)w;    w += (size_t)NB * NA;
  p.cost   = w;          w += (size_t)NB * NG * NA;
  p.thrc   = w;          w += (size_t)NB * NG;
  p.thri   = (int*)w;    w += (size_t)NB * NG;
  p.acc    = w;          w += 4;

  hipMemsetAsync(p.acc, 0, 4 * sizeof(float), stream);

  dim3 gd((NA + 255) / 256, NB);
  k_decode<<<gd, 256, 0, stream>>>(p);
  k_topk<<<NB * NG, 256, 0, stream>>>(p);
  k_match<<<gd, 256, 0, stream>>>(p);
  k_final<<<1, 1, 0, stream>>>(p, (float*)d_out);
}

// Round 3
// 303.075 us; speedup vs baseline: 1.9199x; 1.2289x over previous
//
#include <hip/hip_runtime.h>
#include <cstdint>
#include <cstddef>

#define NB 32
#define NG 30
#define NA 8400
#define NC 80
#define TKB 512   // k_topk block size

struct Params {
  const float* f8; const float* f16; const float* f32; const float* lab;
  float* bbox;    // [NB*NA*4] decoded cx,cy,w,h
  float* objlog;  // [NB*NA]   raw obj logit
  float* base_;   // [NB*NA]   -sum_c log(1-p_c+eps)
  int*   aok;     // [NB*NA]   anchor_ok
  float* cost;    // [NB*NG*NA] full cost matrix (computed once in K3)
  float* thrc;    // [NB*NG]   dyn_k-th smallest cost
  int*   thri;    // [NB*NG]   its anchor index (stable-sort tiebreak)
  float* acc;     // [4] loss_iou, loss_obj, loss_cls, num_fg
};

__device__ __forceinline__ float sigm(float x) { return 1.0f / (1.0f + expf(-x)); }

__device__ __forceinline__ void anchor_geom(int a, int& x, int& y, int& W, int& hw,
                                            float& stride, int& lvl) {
  if (a < 6400)      { W = 80; hw = 6400; stride = 8.f;  lvl = 0; int i = a;        y = i / 80; x = i - y * 80; }
  else if (a < 8000) { W = 40; hw = 1600; stride = 16.f; lvl = 1; int i = a - 6400; y = i / 40; x = i - y * 40; }
  else               { W = 20; hw = 400;  stride = 32.f; lvl = 2; int i = a - 8000; y = i / 20; x = i - y * 20; }
}

// K1: decode bbox/obj, per-anchor cls "base" term, anchor_ok
__global__ __launch_bounds__(256) void k_decode(Params p) {
  __shared__ float sgt[NG * 5];
  int b = blockIdx.y;
  int tid = threadIdx.x;
  if (tid < NG * 5) sgt[tid] = p.lab[(size_t)b * NG * 5 + tid];
  __syncthreads();
  int a = blockIdx.x * 256 + tid;
  if (a >= NA) return;

  int x, y, W, hw, lvl; float stride;
  anchor_geom(a, x, y, W, hw, stride, lvl);
  const float* f = (lvl == 0) ? p.f8 : (lvl == 1) ? p.f16 : p.f32;
  const float* fb = f + (size_t)b * 85 * hw;
  int idx = y * W + x;

  float tx = fb[idx];
  float ty = fb[hw + idx];
  float tw = fb[2 * hw + idx];
  float th = fb[3 * hw + idx];
  float ob = fb[4 * hw + idx];

  float cx = (tx + (float)x) * stride;
  float cy = (ty + (float)y) * stride;
  float w  = expf(tw) * stride;
  float h  = expf(th) * stride;

  float* bb = p.bbox + ((size_t)(b * NA + a)) * 4;
  bb[0] = cx; bb[1] = cy; bb[2] = w; bb[3] = h;
  p.objlog[b * NA + a] = ob;

  float po = sigm(ob);
  float bs = 0.0f;
  // same sequential accumulation order as before (bit-identical base_),
  // unroll batches the independent loads.
#pragma unroll 8
  for (int c = 0; c < NC; c++) {
    float xl = fb[(size_t)(5 + c) * hw + idx];
    float pc = sigm(xl);
    float pr = sqrtf(pc * po);
    bs -= logf(1.0f - pr + 1e-8f);
  }
  p.base_[b * NA + a] = bs;

  float xc = ((float)x + 0.5f) * stride;
  float yc = ((float)y + 0.5f) * stride;
  float r = 2.5f * stride;
  int ok = 0;
#pragma unroll
  for (int g = 0; g < NG; g++) {
    float gx = sgt[g * 5], gy = sgt[g * 5 + 1], gw = sgt[g * 5 + 2], gh = sgt[g * 5 + 3];
    bool inb = (xc > gx - 0.5f * gw) && (xc < gx + 0.5f * gw) &&
               (yc > gy - 0.5f * gh) && (yc < gy + 0.5f * gh);
    bool inc = (xc > gx - r) && (xc < gx + r) && (yc > gy - r) && (yc < gy + r);
    ok |= (inb || inc) ? 1 : 0;
  }
  p.aok[b * NA + a] = ok;
}

// block-wide argmax of (v, carry i); result on ALL threads. Needs full waves.
__device__ __forceinline__ void block_argmax(float& v, int& i, int tid,
                                             float* swv, int* swi) {
#pragma unroll
  for (int off = 32; off; off >>= 1) {
    float v2 = __shfl_down(v, off, 64);
    int   i2 = __shfl_down(i, off, 64);
    if (v2 > v) { v = v2; i = i2; }
  }
  int wv = tid >> 6;
  if ((tid & 63) == 0) { swv[wv] = v; swi[wv] = i; }
  __syncthreads();
  float bv = swv[0]; int bi = swi[0];
#pragma unroll
  for (int w = 1; w < TKB / 64; w++) {
    if (swv[w] > bv) { bv = swv[w]; bi = swi[w]; }
  }
  v = bv; i = bi;
  __syncthreads();
}

// block-wide lexicographic min of (c, anchor idx i); result on ALL threads.
__device__ __forceinline__ void block_argmin_lex(float& c, int& i, int tid,
                                                 float* swv, int* swi) {
#pragma unroll
  for (int off = 32; off; off >>= 1) {
    float c2 = __shfl_down(c, off, 64);
    int   i2 = __shfl_down(i, off, 64);
    if (c2 < c || (c2 == c && i2 < i)) { c = c2; i = i2; }
  }
  int wv = tid >> 6;
  if ((tid & 63) == 0) { swv[wv] = c; swi[wv] = i; }
  __syncthreads();
  float bc = swv[0]; int bi = swi[0];
#pragma unroll
  for (int w = 1; w < TKB / 64; w++) {
    float c2 = swv[w]; int i2 = swi[w];
    if (c2 < bc || (c2 == bc && i2 < bi)) { bc = c2; bi = i2; }
  }
  c = bc; i = bi;
  __syncthreads();
}

// K3: one block per (b,g). Computes cost (stored to p.cost) + iou inline.
// Top-10 IoUs -> dyn_k; dyn_k-th smallest (cost,idx) -> threshold.
__global__ __launch_bounds__(TKB) void k_topk(Params p) {
  __shared__ float swv[TKB / 64];
  __shared__ int   swi[TKB / 64];
  int bg = blockIdx.x;
  int b = bg / NG, g = bg % NG;
  int tid = threadIdx.x;

  const float* gt = p.lab + ((size_t)b * NG + g) * 5;
  float gx = gt[0], gy = gt[1], gw = gt[2], gh = gt[3];
  int cg = (int)gt[4];
  float area_g = gw * gh;
  float glx = gx - 0.5f * gw, grx = gx + 0.5f * gw;
  float gty = gy - 0.5f * gh, gby = gy + 0.5f * gh;

  float v[10];                 // local top-10 ious, descending
  float cv[10]; int ci[10];    // local 10 smallest (cost, idx), ascending
#pragma unroll
  for (int j = 0; j < 10; j++) { v[j] = -1.0f; cv[j] = 3.4e38f; ci[j] = 0x7FFFFFFF; }

  float* crow = p.cost + (size_t)bg * NA;

  for (int a = tid; a < NA; a += TKB) {
    int x, y, W, hw, lvl; float stride;
    anchor_geom(a, x, y, W, hw, stride, lvl);
    const float* f = (lvl == 0) ? p.f8 : (lvl == 1) ? p.f16 : p.f32;
    const float* fb = f + (size_t)b * 85 * hw;
    int idx = y * W + x;

    float4 bb = *(const float4*)(p.bbox + ((size_t)(b * NA + a)) * 4);
    int aok = p.aok[b * NA + a];
    float xl = fb[(size_t)(5 + cg) * hw + idx];
    float ol = p.objlog[b * NA + a];
    float bsv = p.base_[b * NA + a];

    float px = bb.x, py = bb.y, pw = bb.z, ph = bb.w;

    // pairwise IoU (gt vs decoded pred)
    float tlx = fmaxf(glx, px - pw * 0.5f);
    float tly = fmaxf(gty, py - ph * 0.5f);
    float brx = fminf(grx, px + pw * 0.5f);
    float bry = fminf(gby, py + ph * 0.5f);
    float inter = ((tlx < brx) && (tly < bry)) ? (brx - tlx) * (bry - tly) : 0.0f;
    float iou = inter / (area_g + pw * ph - inter + 1e-16f);
    iou = aok ? iou : 0.0f;
    float iou_cost = -logf(iou + 1e-8f);

    // geometry gates
    float xc = ((float)x + 0.5f) * stride;
    float yc = ((float)y + 0.5f) * stride;
    bool inb = (xc > glx) && (xc < grx) && (yc > gty) && (yc < gby);
    float r = 2.5f * stride;
    bool inc = (xc > gx - r) && (xc < gx + r) && (yc > gy - r) && (yc < gy + r);
    bool in_both = inb && inc;

    // cls cost for this gt's class
    float po = sigm(ol);
    float pc = sigm(xl);
    float pr = sqrtf(pc * po);
    float logp = logf(pr + 1e-8f);
    float log1mp = logf(1.0f - pr + 1e-8f);
    float cls_cost = bsv - (logp - log1mp);

    float c = cls_cost + 3.0f * iou_cost;
    c = c + (in_both ? 0.0f : 100000.0f);
    c = c + (aok ? 0.0f : 1000000000.0f);
    crow[a] = c;

    if (iou > v[9]) {
      int j = 9;
      while (j > 0 && iou > v[j - 1]) { v[j] = v[j - 1]; j--; }
      v[j] = iou;
    }
    if (c < cv[9] || (c == cv[9] && a < ci[9])) {
      int j = 9;
      while (j > 0 && (c < cv[j - 1] || (c == cv[j - 1] && a < ci[j - 1]))) {
        cv[j] = cv[j - 1]; ci[j] = ci[j - 1]; j--;
      }
      cv[j] = c; ci[j] = a;
    }
  }

  // merge top-10 ious (pop global max 10x), sum in descending order
  float sum = 0.0f; int ptr = 0;
  for (int it = 0; it < 10; it++) {
    float mv = (ptr < 10) ? v[ptr] : -1e30f;
    int   mi = tid;
    block_argmax(mv, mi, tid, swv, swi);
    if (tid == mi) ptr++;
    sum += mv;
  }
  int dynk = (int)sum;
  if (dynk < 1) dynk = 1;

  // pop global lexicographic min dynk times; last popped = threshold pair
  ptr = 0;
  float thc = 0.0f; int thi = 0;
  for (int it = 0; it < dynk; it++) {
    float mc = (ptr < 10) ? cv[ptr] : 3.4e38f;
    int   mi = (ptr < 10) ? ci[ptr] : 0x7FFFFFFF;
    block_argmin_lex(mc, mi, tid, swv, swi);
    thc = mc; thi = mi;
    if (ptr < 10 && ci[ptr] == thi) ptr++;  // anchor idx unique -> one owner advances
  }
  if (tid == 0) { p.thrc[bg] = thc; p.thri[bg] = thi; }
}

__device__ __forceinline__ float block_sum(float val, volatile float* sw) {
#pragma unroll
  for (int off = 32; off > 0; off >>= 1) val += __shfl_down(val, off, 64);
  int lane = threadIdx.x & 63, wv = threadIdx.x >> 6;
  __syncthreads();
  if (lane == 0) sw[wv] = val;
  __syncthreads();
  float r = 0.0f;
  if (threadIdx.x == 0) r = sw[0] + sw[1] + sw[2] + sw[3];
  return r;
}

// K4: per (b,a) matching (reads stored cost matrix) + loss contributions
__global__ __launch_bounds__(256) void k_match(Params p) {
  __shared__ float sth[NG];
  __shared__ int   sti[NG];
  __shared__ float sred[4];
  int b = blockIdx.y;
  int tid = threadIdx.x;
  if (tid < NG) { sth[tid] = p.thrc[b * NG + tid]; sti[tid] = p.thri[b * NG + tid]; }
  __syncthreads();
  int a = blockIdx.x * 256 + tid;
  bool valid = a < NA;

  float l_iou = 0.0f, l_obj = 0.0f, l_cls = 0.0f, l_nfg = 0.0f;
  bool fg = false; float pred_iou = 0.0f; int cg_ = 0;

  if (valid) {
    int aok = p.aok[b * NA + a];
    const float* ccol = p.cost + (size_t)b * NG * NA + a;
    float cc[NG];
#pragma unroll
    for (int g = 0; g < NG; g++) cc[g] = ccol[(size_t)g * NA];  // all 30 loads in flight

    unsigned mask = 0; int am = 0;
    float minc = 3.4e38f; int ming = 0;
#pragma unroll
    for (int g = 0; g < NG; g++) {
      float c = cc[g];
      if (c < minc) { minc = c; ming = g; }
      bool m = aok && (c < sth[g] || (c == sth[g] && a <= sti[g]));
      if (m) { mask |= (1u << g); am++; }
    }
    if (am > 1) mask = (1u << ming);
    fg = (mask != 0u);

    float ol = p.objlog[b * NA + a];
    float tfg = fg ? 1.0f : 0.0f;
    l_obj = fmaxf(ol, 0.0f) - ol * tfg + log1pf(expf(-fabsf(ol)));

    if (fg) {
      l_nfg = 1.0f;
      int mg = __ffs(mask) - 1;

      float4 bbv = *(const float4*)(p.bbox + ((size_t)(b * NA + a)) * 4);
      float px = bbv.x, py = bbv.y, pw = bbv.z, ph = bbv.w;

      // pred_iou = sum over matched g of pairwise IoU (all matched g have aok=1)
      unsigned mm = mask;
      while (mm) {
        int g = __ffs(mm) - 1; mm &= mm - 1u;
        const float* gtg = p.lab + ((size_t)b * NG + g) * 5;
        float gx = gtg[0], gy = gtg[1], gw = gtg[2], gh = gtg[3];
        float tlx = fmaxf(gx - gw * 0.5f, px - pw * 0.5f);
        float tly = fmaxf(gy - gh * 0.5f, py - ph * 0.5f);
        float brx = fminf(gx + gw * 0.5f, px + pw * 0.5f);
        float bry = fminf(gy + gh * 0.5f, py + ph * 0.5f);
        float inter = ((tlx < brx) && (tly < bry)) ? (brx - tlx) * (bry - tly) : 0.0f;
        pred_iou += inter / (gw * gh + pw * ph - inter + 1e-16f);
      }

      const float* gtm = p.lab + ((size_t)b * NG + mg) * 5;
      float gx = gtm[0], gy = gtm[1], gw = gtm[2], gh = gtm[3];
      cg_ = (int)gtm[4];

      float tlx = fmaxf(px - pw * 0.5f, gx - gw * 0.5f);
      float tly = fmaxf(py - ph * 0.5f, gy - gh * 0.5f);
      float brx = fminf(px + pw * 0.5f, gx + gw * 0.5f);
      float bry = fminf(py + ph * 0.5f, gy + gh * 0.5f);
      float ap = pw * ph, ag = gw * gh;
      float ai = ((tlx < brx) && (tly < bry)) ? (brx - tlx) * (bry - tly) : 0.0f;
      float iouE = ai / (ap + ag - ai + 1e-16f);
      l_iou = 1.0f - iouE * iouE;
    }
  }

  // wave-cooperative cls-loss for fg anchors: all 64 lanes split the 80 classes
  unsigned long long fgb = __ballot(fg);
  int lane = tid & 63;
  while (fgb) {
    int src = __ffsll(fgb) - 1;
    fgb &= fgb - 1ull;
    int   aa   = __shfl(a, src, 64);
    float piou = __shfl(pred_iou, src, 64);
    int   ccg  = __shfl(cg_, src, 64);

    int x, y, W, hw, lvl; float stride;
    anchor_geom(aa, x, y, W, hw, stride, lvl);
    const float* f = (lvl == 0) ? p.f8 : (lvl == 1) ? p.f16 : p.f32;
    const float* fb = f + (size_t)b * 85 * hw;
    int idx = y * W + x;

    float part = 0.0f;
#pragma unroll
    for (int c0 = 0; c0 < NC; c0 += 64) {
      int c = c0 + lane;
      if (c < NC) {
        float xl = fb[(size_t)(5 + c) * hw + idx];
        float t = (c == ccg) ? piou : 0.0f;
        part += fmaxf(xl, 0.0f) - xl * t + log1pf(expf(-fabsf(xl)));
      }
    }
#pragma unroll
    for (int off = 32; off; off >>= 1) part += __shfl_down(part, off, 64);
    if (lane == 0) l_cls += part;
  }

  float s0 = block_sum(l_iou, sred);
  float s1 = block_sum(l_obj, sred);
  float s2 = block_sum(l_cls, sred);
  float s3 = block_sum(l_nfg, sred);
  if (tid == 0) {
    atomicAdd(&p.acc[0], s0);
    atomicAdd(&p.acc[1], s1);
    atomicAdd(&p.acc[2], s2);
    atomicAdd(&p.acc[3], s3);
  }
}

__global__ void k_final(Params p, float* out) {
  float li = p.acc[0], lo = p.acc[1], lc = p.acc[2], nf = p.acc[3];
  float nfg = fmaxf(nf, 1.0f);
  out[0] = (5.0f * li + 0.1f * lo + lc) / nfg;
}

extern "C" void kernel_launch(void* const* d_in, const int* in_sizes, int n_in,
                              void* d_out, int out_size, void* d_ws, size_t ws_size,
                              hipStream_t stream) {
  Params p;
  p.f8  = (const float*)d_in[0];
  p.f16 = (const float*)d_in[1];
  p.f32 = (const float*)d_in[2];
  p.lab = (const float*)d_in[3];

  float* w = (float*)d_ws;
  p.bbox   = w;          w += (size_t)NB * NA * 4;
  p.objlog = w;          w += (size_t)NB * NA;
  p.base_  = w;          w += (size_t)NB * NA;
  p.aok    = (int*)w;    w += (size_t)NB * NA;
  p.cost   = w;          w += (size_t)NB * NG * NA;
  p.thrc   = w;          w += (size_t)NB * NG;
  p.thri   = (int*)w;    w += (size_t)NB * NG;
  p.acc    = w;          w += 4;

  hipMemsetAsync(p.acc, 0, 4 * sizeof(float), stream);

  dim3 gd((NA + 255) / 256, NB);
  k_decode<<<gd, 256, 0, stream>>>(p);
  k_topk<<<NB * NG, TKB, 0, stream>>>(p);
  k_match<<<gd, 256, 0, stream>>>(p);
  k_final<<<1, 1, 0, stream>>>(p, (float*)d_out);
}

// Round 4
// 297.122 us; speedup vs baseline: 1.9584x; 1.0200x over previous
//
#include <hip/hip_runtime.h>
#include <cstdint>
#include <cstddef>

#define NB 32
#define NG 30
#define NA 8400
#define NC 80
#define SELB 256  // k_sel block size

struct Params {
  const float* f8; const float* f16; const float* f32; const float* lab;
  float* objlog;  // [NB*NA]    raw obj logit
  int*   aok;     // [NB*NA]    anchor_ok
  float* cost;    // [NB*NG*NA] cost matrix (computed once in k_cost)
  float* ioum;    // [NB*NG*NA] iou matrix (aok-zeroed, as reference)
  float* thrc;    // [NB*NG]    dyn_k-th smallest cost
  int*   thri;    // [NB*NG]    its anchor index (stable-sort tiebreak)
  float* acc;     // [4] loss_iou, loss_obj, loss_cls, num_fg
};

__device__ __forceinline__ float fsigm(float x) { return 1.0f / (1.0f + __expf(-x)); }

__device__ __forceinline__ void anchor_geom(int a, int& x, int& y, int& W, int& hw,
                                            float& stride, int& lvl) {
  if (a < 6400)      { W = 80; hw = 6400; stride = 8.f;  lvl = 0; int i = a;        y = i / 80; x = i - y * 80; }
  else if (a < 8000) { W = 40; hw = 1600; stride = 16.f; lvl = 1; int i = a - 6400; y = i / 40; x = i - y * 40; }
  else               { W = 20; hw = 400;  stride = 32.f; lvl = 2; int i = a - 8000; y = i / 20; x = i - y * 20; }
}

// K1: one thread per (b,a). Decode + base + aok ONCE, then loop g computing
// cost & iou, stored to the [b][g][a] matrices (coalesced across a).
__global__ __launch_bounds__(256) void k_cost(Params p) {
  __shared__ float sgt[NG * 5];
  int b = blockIdx.y;
  int tid = threadIdx.x;
  if (tid < NG * 5) sgt[tid] = p.lab[(size_t)b * NG * 5 + tid];
  __syncthreads();
  int a = blockIdx.x * 256 + tid;
  if (a >= NA) return;

  int x, y, W, hw, lvl; float stride;
  anchor_geom(a, x, y, W, hw, stride, lvl);
  const float* f = (lvl == 0) ? p.f8 : (lvl == 1) ? p.f16 : p.f32;
  const float* fb = f + (size_t)b * 85 * hw;
  int idx = y * W + x;

  float tx = fb[idx];
  float ty = fb[hw + idx];
  float tw = fb[2 * hw + idx];
  float th = fb[3 * hw + idx];
  float ob = fb[4 * hw + idx];

  float px = (tx + (float)x) * stride;
  float py = (ty + (float)y) * stride;
  float pw = __expf(tw) * stride;
  float ph = __expf(th) * stride;
  p.objlog[b * NA + a] = ob;

  float po = fsigm(ob);
  float bs = 0.0f;
#pragma unroll 8
  for (int c = 0; c < NC; c++) {
    float xl = fb[(size_t)(5 + c) * hw + idx];
    float pc = fsigm(xl);
    float pr = sqrtf(pc * po);
    bs -= __logf(1.0f - pr + 1e-8f);
  }

  float xc = ((float)x + 0.5f) * stride;
  float yc = ((float)y + 0.5f) * stride;
  float r = 2.5f * stride;
  int ok = 0;
#pragma unroll
  for (int g = 0; g < NG; g++) {
    float gx = sgt[g * 5], gy = sgt[g * 5 + 1], gw = sgt[g * 5 + 2], gh = sgt[g * 5 + 3];
    bool inb = (xc > gx - 0.5f * gw) && (xc < gx + 0.5f * gw) &&
               (yc > gy - 0.5f * gh) && (yc < gy + 0.5f * gh);
    bool inc = (xc > gx - r) && (xc < gx + r) && (yc > gy - r) && (yc < gy + r);
    ok |= (inb || inc) ? 1 : 0;
  }
  p.aok[b * NA + a] = ok;

  float hwd = pw * 0.5f, hhd = ph * 0.5f;
  float plx = px - hwd, prx = px + hwd;
  float pty = py - hhd, pby = py + hhd;
  float area_p = pw * ph;
  size_t cbase = (size_t)b * NG * NA + a;

  for (int g = 0; g < NG; g++) {
    float gx = sgt[g * 5], gy = sgt[g * 5 + 1], gw = sgt[g * 5 + 2], gh = sgt[g * 5 + 3];
    int cg = (int)sgt[g * 5 + 4];
    float glx = gx - 0.5f * gw, grx = gx + 0.5f * gw;
    float gty = gy - 0.5f * gh, gby = gy + 0.5f * gh;

    float tlx = fmaxf(glx, plx);
    float tly = fmaxf(gty, pty);
    float brx = fminf(grx, prx);
    float bry = fminf(gby, pby);
    float inter = ((tlx < brx) && (tly < bry)) ? (brx - tlx) * (bry - tly) : 0.0f;
    float iou = inter / (gw * gh + area_p - inter + 1e-16f);
    iou = ok ? iou : 0.0f;
    float iou_cost = -__logf(iou + 1e-8f);

    bool inb = (xc > glx) && (xc < grx) && (yc > gty) && (yc < gby);
    bool inc = (xc > gx - r) && (xc < gx + r) && (yc > gy - r) && (yc < gy + r);

    float xl = fb[(size_t)(5 + cg) * hw + idx];
    float pc = fsigm(xl);
    float pr = sqrtf(pc * po);
    float cls_cost = bs - (__logf(pr + 1e-8f) - __logf(1.0f - pr + 1e-8f));

    float c = cls_cost + 3.0f * iou_cost;
    c = c + ((inb && inc) ? 0.0f : 100000.0f);
    c = c + (ok ? 0.0f : 1000000000.0f);
    p.cost[cbase + (size_t)g * NA] = c;
    p.ioum[cbase + (size_t)g * NA] = iou;
  }
}

// block-wide argmax of (v, carry i); result on ALL threads.
__device__ __forceinline__ void block_argmax(float& v, int& i, int tid,
                                             float* swv, int* swi) {
#pragma unroll
  for (int off = 32; off; off >>= 1) {
    float v2 = __shfl_down(v, off, 64);
    int   i2 = __shfl_down(i, off, 64);
    if (v2 > v) { v = v2; i = i2; }
  }
  int wv = tid >> 6;
  if ((tid & 63) == 0) { swv[wv] = v; swi[wv] = i; }
  __syncthreads();
  float bv = swv[0]; int bi = swi[0];
#pragma unroll
  for (int w = 1; w < SELB / 64; w++) {
    if (swv[w] > bv) { bv = swv[w]; bi = swi[w]; }
  }
  v = bv; i = bi;
  __syncthreads();
}

// block-wide lexicographic min of (c, anchor idx i); result on ALL threads.
__device__ __forceinline__ void block_argmin_lex(float& c, int& i, int tid,
                                                 float* swv, int* swi) {
#pragma unroll
  for (int off = 32; off; off >>= 1) {
    float c2 = __shfl_down(c, off, 64);
    int   i2 = __shfl_down(i, off, 64);
    if (c2 < c || (c2 == c && i2 < i)) { c = c2; i = i2; }
  }
  int wv = tid >> 6;
  if ((tid & 63) == 0) { swv[wv] = c; swi[wv] = i; }
  __syncthreads();
  float bc = swv[0]; int bi = swi[0];
#pragma unroll
  for (int w = 1; w < SELB / 64; w++) {
    float c2 = swv[w]; int i2 = swi[w];
    if (c2 < bc || (c2 == bc && i2 < bi)) { bc = c2; bi = i2; }
  }
  c = bc; i = bi;
  __syncthreads();
}

// K2: one block per (b,g). Reads stored iou/cost rows.
// Top-10 IoUs -> dyn_k; dyn_k-th smallest (cost,idx) -> threshold.
__global__ __launch_bounds__(SELB) void k_sel(Params p) {
  __shared__ float swv[SELB / 64];
  __shared__ int   swi[SELB / 64];
  int bg = blockIdx.x;
  int tid = threadIdx.x;

  const float* crow = p.cost + (size_t)bg * NA;
  const float* irow = p.ioum + (size_t)bg * NA;

  float v[10];                 // local top-10 ious, descending
  float cv[10]; int ci[10];    // local 10 smallest (cost, idx), ascending
#pragma unroll
  for (int j = 0; j < 10; j++) { v[j] = -1.0f; cv[j] = 3.4e38f; ci[j] = 0x7FFFFFFF; }

  for (int a = tid; a < NA; a += SELB) {
    float iou = irow[a];
    float c = crow[a];
    if (iou > v[9]) {
      int j = 9;
      while (j > 0 && iou > v[j - 1]) { v[j] = v[j - 1]; j--; }
      v[j] = iou;
    }
    if (c < cv[9] || (c == cv[9] && a < ci[9])) {
      int j = 9;
      while (j > 0 && (c < cv[j - 1] || (c == cv[j - 1] && a < ci[j - 1]))) {
        cv[j] = cv[j - 1]; ci[j] = ci[j - 1]; j--;
      }
      cv[j] = c; ci[j] = a;
    }
  }

  // merge top-10 ious (pop global max 10x)
  float sum = 0.0f; int ptr = 0;
  for (int it = 0; it < 10; it++) {
    float mv = (ptr < 10) ? v[ptr] : -1e30f;
    int   mi = tid;
    block_argmax(mv, mi, tid, swv, swi);
    if (tid == mi) ptr++;
    sum += mv;
  }
  int dynk = (int)sum;
  if (dynk < 1) dynk = 1;

  // pop global lexicographic min dynk times; last popped = threshold pair
  ptr = 0;
  float thc = 0.0f; int thi = 0;
  for (int it = 0; it < dynk; it++) {
    float mc = (ptr < 10) ? cv[ptr] : 3.4e38f;
    int   mi = (ptr < 10) ? ci[ptr] : 0x7FFFFFFF;
    block_argmin_lex(mc, mi, tid, swv, swi);
    thc = mc; thi = mi;
    if (ptr < 10 && ci[ptr] == thi) ptr++;  // anchor idx unique -> one owner advances
  }
  if (tid == 0) { p.thrc[bg] = thc; p.thri[bg] = thi; }
}

__device__ __forceinline__ float block_sum(float val, volatile float* sw) {
#pragma unroll
  for (int off = 32; off > 0; off >>= 1) val += __shfl_down(val, off, 64);
  int lane = threadIdx.x & 63, wv = threadIdx.x >> 6;
  __syncthreads();
  if (lane == 0) sw[wv] = val;
  __syncthreads();
  float r = 0.0f;
  if (threadIdx.x == 0) r = sw[0] + sw[1] + sw[2] + sw[3];
  return r;
}

// K3: per (b,a) matching (stored cost + iou) + loss contributions
__global__ __launch_bounds__(256) void k_match(Params p) {
  __shared__ float sth[NG];
  __shared__ int   sti[NG];
  __shared__ float sred[4];
  int b = blockIdx.y;
  int tid = threadIdx.x;
  if (tid < NG) { sth[tid] = p.thrc[b * NG + tid]; sti[tid] = p.thri[b * NG + tid]; }
  __syncthreads();
  int a = blockIdx.x * 256 + tid;
  bool valid = a < NA;

  float l_iou = 0.0f, l_obj = 0.0f, l_cls = 0.0f, l_nfg = 0.0f;
  bool fg = false; float pred_iou = 0.0f; int cg_ = 0;

  if (valid) {
    int aok = p.aok[b * NA + a];
    const float* ccol = p.cost + (size_t)b * NG * NA + a;
    float cc[NG];
#pragma unroll
    for (int g = 0; g < NG; g++) cc[g] = ccol[(size_t)g * NA];  // all 30 loads in flight

    unsigned mask = 0; int am = 0;
    float minc = 3.4e38f; int ming = 0;
#pragma unroll
    for (int g = 0; g < NG; g++) {
      float c = cc[g];
      if (c < minc) { minc = c; ming = g; }
      bool m = aok && (c < sth[g] || (c == sth[g] && a <= sti[g]));
      if (m) { mask |= (1u << g); am++; }
    }
    if (am > 1) mask = (1u << ming);
    fg = (mask != 0u);

    float ol = p.objlog[b * NA + a];
    float tfg = fg ? 1.0f : 0.0f;
    l_obj = fmaxf(ol, 0.0f) - ol * tfg + log1pf(expf(-fabsf(ol)));

    if (fg) {
      l_nfg = 1.0f;
      int mg = __ffs(mask) - 1;
      const float* icol = p.ioum + (size_t)b * NG * NA + a;

      unsigned mm = mask;
      while (mm) {
        int g = __ffs(mm) - 1; mm &= mm - 1u;
        pred_iou += icol[(size_t)g * NA];
      }
      // iou_elem(pred, gt[mg]) is bit-identical to the pairwise IoU stored
      float i0 = icol[(size_t)mg * NA];
      l_iou = 1.0f - i0 * i0;
      cg_ = (int)p.lab[((size_t)b * NG + mg) * 5 + 4];
    }
  }

  // wave-cooperative cls-loss for fg anchors: all 64 lanes split the 80 classes
  unsigned long long fgb = __ballot(fg);
  int lane = tid & 63;
  while (fgb) {
    int src = __ffsll(fgb) - 1;
    fgb &= fgb - 1ull;
    int   aa   = __shfl(a, src, 64);
    float piou = __shfl(pred_iou, src, 64);
    int   ccg  = __shfl(cg_, src, 64);

    int x, y, W, hw, lvl; float stride;
    anchor_geom(aa, x, y, W, hw, stride, lvl);
    const float* f = (lvl == 0) ? p.f8 : (lvl == 1) ? p.f16 : p.f32;
    const float* fb = f + (size_t)b * 85 * hw;
    int idx = y * W + x;

    float part = 0.0f;
#pragma unroll
    for (int c0 = 0; c0 < NC; c0 += 64) {
      int c = c0 + lane;
      if (c < NC) {
        float xl = fb[(size_t)(5 + c) * hw + idx];
        float t = (c == ccg) ? piou : 0.0f;
        part += fmaxf(xl, 0.0f) - xl * t + log1pf(expf(-fabsf(xl)));
      }
    }
#pragma unroll
    for (int off = 32; off; off >>= 1) part += __shfl_down(part, off, 64);
    if (lane == 0) l_cls += part;
  }

  float s0 = block_sum(l_iou, sred);
  float s1 = block_sum(l_obj, sred);
  float s2 = block_sum(l_cls, sred);
  float s3 = block_sum(l_nfg, sred);
  if (tid == 0) {
    atomicAdd(&p.acc[0], s0);
    atomicAdd(&p.acc[1], s1);
    atomicAdd(&p.acc[2], s2);
    atomicAdd(&p.acc[3], s3);
  }
}

__global__ void k_final(Params p, float* out) {
  float li = p.acc[0], lo = p.acc[1], lc = p.acc[2], nf = p.acc[3];
  float nfg = fmaxf(nf, 1.0f);
  out[0] = (5.0f * li + 0.1f * lo + lc) / nfg;
}

extern "C" void kernel_launch(void* const* d_in, const int* in_sizes, int n_in,
                              void* d_out, int out_size, void* d_ws, size_t ws_size,
                              hipStream_t stream) {
  Params p;
  p.f8  = (const float*)d_in[0];
  p.f16 = (const float*)d_in[1];
  p.f32 = (const float*)d_in[2];
  p.lab = (const float*)d_in[3];

  float* w = (float*)d_ws;
  p.objlog = w;          w += (size_t)NB * NA;
  p.aok    = (int*)w;    w += (size_t)NB * NA;
  p.cost   = w;          w += (size_t)NB * NG * NA;
  p.ioum   = w;          w += (size_t)NB * NG * NA;
  p.thrc   = w;          w += (size_t)NB * NG;
  p.thri   = (int*)w;    w += (size_t)NB * NG;
  p.acc    = w;          w += 4;

  hipMemsetAsync(p.acc, 0, 4 * sizeof(float), stream);

  dim3 gd((NA + 255) / 256, NB);
  k_cost<<<gd, 256, 0, stream>>>(p);
  k_sel<<<NB * NG, SELB, 0, stream>>>(p);
  k_match<<<gd, 256, 0, stream>>>(p);
  k_final<<<1, 1, 0, stream>>>(p, (float*)d_out);
}

// Round 5
// 295.006 us; speedup vs baseline: 1.9724x; 1.0072x over previous
//
#include <hip/hip_runtime.h>
#include <cstdint>
#include <cstddef>

#define NB 32
#define NG 30
#define NA 8400
#define NC 80
#define SELB 256  // k_sel block size

struct Params {
  const float* f8; const float* f16; const float* f32; const float* lab;
  float*    bbox;   // [NB*NA] float4 decoded cx,cy,w,h
  float*    objlog; // [NB*NA] raw obj logit
  float*    cost;   // [NB*NG*NA] cost matrix (computed once in k_cost)
  unsigned* mmask;  // [NB*NA] bit g set => anchor popped (matched pre-dedup) for gt g
  float*    acc;    // [4] loss_iou, loss_obj, loss_cls, num_fg
};

__device__ __forceinline__ float fsigm(float x) {
  return __fdividef(1.0f, 1.0f + __expf(-x));
}

__device__ __forceinline__ void anchor_geom(int a, int& x, int& y, int& W, int& hw,
                                            float& stride, int& lvl) {
  if (a < 6400)      { W = 80; hw = 6400; stride = 8.f;  lvl = 0; int i = a;        y = i / 80; x = i - y * 80; }
  else if (a < 8000) { W = 40; hw = 1600; stride = 16.f; lvl = 1; int i = a - 6400; y = i / 40; x = i - y * 40; }
  else               { W = 20; hw = 400;  stride = 32.f; lvl = 2; int i = a - 8000; y = i / 20; x = i - y * 20; }
}

// pairwise IoU, identical expression everywhere (k_cost / k_sel / k_match)
__device__ __forceinline__ float pair_iou(float px, float py, float pw, float ph,
                                          float glx, float gty, float grx, float gby,
                                          float area_g) {
  float tlx = fmaxf(glx, px - pw * 0.5f);
  float tly = fmaxf(gty, py - ph * 0.5f);
  float brx = fminf(grx, px + pw * 0.5f);
  float bry = fminf(gby, py + ph * 0.5f);
  float inter = ((tlx < brx) && (tly < bry)) ? (brx - tlx) * (bry - tly) : 0.0f;
  return __fdividef(inter, area_g + pw * ph - inter + 1e-16f);
}

// K1: one thread per (b,a). Decode + base + aok once, then g-loop writes cost only.
__global__ __launch_bounds__(256) void k_cost(Params p) {
  __shared__ float sgt[NG * 5];
  int b = blockIdx.y;
  int tid = threadIdx.x;
  if (tid < NG * 5) sgt[tid] = p.lab[(size_t)b * NG * 5 + tid];
  __syncthreads();
  int a = blockIdx.x * 256 + tid;
  if (a >= NA) return;

  int x, y, W, hw, lvl; float stride;
  anchor_geom(a, x, y, W, hw, stride, lvl);
  const float* f = (lvl == 0) ? p.f8 : (lvl == 1) ? p.f16 : p.f32;
  const float* fb = f + (size_t)b * 85 * hw;
  int idx = y * W + x;

  float tx = fb[idx];
  float ty = fb[hw + idx];
  float tw = fb[2 * hw + idx];
  float th = fb[3 * hw + idx];
  float ob = fb[4 * hw + idx];

  float px = (tx + (float)x) * stride;
  float py = (ty + (float)y) * stride;
  float pw = __expf(tw) * stride;
  float ph = __expf(th) * stride;
  ((float4*)p.bbox)[(size_t)b * NA + a] = make_float4(px, py, pw, ph);
  p.objlog[b * NA + a] = ob;

  float po = fsigm(ob);
  float bs = 0.0f;
#pragma unroll 8
  for (int c = 0; c < NC; c++) {
    float xl = fb[(size_t)(5 + c) * hw + idx];
    float pc = fsigm(xl);
    float pr = sqrtf(pc * po);
    bs -= __logf(1.0f - pr + 1e-8f);
  }

  float xc = ((float)x + 0.5f) * stride;
  float yc = ((float)y + 0.5f) * stride;
  float r = 2.5f * stride;
  int ok = 0;
#pragma unroll
  for (int g = 0; g < NG; g++) {
    float gx = sgt[g * 5], gy = sgt[g * 5 + 1], gw = sgt[g * 5 + 2], gh = sgt[g * 5 + 3];
    bool inb = (xc > gx - 0.5f * gw) && (xc < gx + 0.5f * gw) &&
               (yc > gy - 0.5f * gh) && (yc < gy + 0.5f * gh);
    bool inc = (xc > gx - r) && (xc < gx + r) && (yc > gy - r) && (yc < gy + r);
    ok |= (inb || inc) ? 1 : 0;
  }

  float area_p = pw * ph;
  size_t cbase = (size_t)b * NG * NA + a;

  for (int g = 0; g < NG; g++) {
    float gx = sgt[g * 5], gy = sgt[g * 5 + 1], gw = sgt[g * 5 + 2], gh = sgt[g * 5 + 3];
    int cg = (int)sgt[g * 5 + 4];
    float glx = gx - 0.5f * gw, grx = gx + 0.5f * gw;
    float gty = gy - 0.5f * gh, gby = gy + 0.5f * gh;

    float iou = pair_iou(px, py, pw, ph, glx, gty, grx, gby, gw * gh);
    iou = ok ? iou : 0.0f;
    float iou_cost = -__logf(iou + 1e-8f);

    bool inb = (xc > glx) && (xc < grx) && (yc > gty) && (yc < gby);
    bool inc = (xc > gx - r) && (xc < gx + r) && (yc > gy - r) && (yc < gy + r);

    float xl = fb[(size_t)(5 + cg) * hw + idx];
    float pc = fsigm(xl);
    float pr = sqrtf(pc * po);
    float cls_cost = bs - (__logf(pr + 1e-8f) - __logf(1.0f - pr + 1e-8f));

    float c = cls_cost + 3.0f * iou_cost;
    c = c + ((inb && inc) ? 0.0f : 100000.0f);
    c = c + (ok ? 0.0f : 1000000000.0f);   // !ok <=> cost >= 1e9 (ok costs < 2e5)
    p.cost[cbase + (size_t)g * NA] = c;
  }
}

// block-wide argmax of (v, carry i); result on ALL threads.
__device__ __forceinline__ void block_argmax(float& v, int& i, int tid,
                                             float* swv, int* swi) {
#pragma unroll
  for (int off = 32; off; off >>= 1) {
    float v2 = __shfl_down(v, off, 64);
    int   i2 = __shfl_down(i, off, 64);
    if (v2 > v) { v = v2; i = i2; }
  }
  int wv = tid >> 6;
  if ((tid & 63) == 0) { swv[wv] = v; swi[wv] = i; }
  __syncthreads();
  float bv = swv[0]; int bi = swi[0];
#pragma unroll
  for (int w = 1; w < SELB / 64; w++) {
    if (swv[w] > bv) { bv = swv[w]; bi = swi[w]; }
  }
  v = bv; i = bi;
  __syncthreads();
}

// block-wide lexicographic min of (c, anchor idx i); result on ALL threads.
__device__ __forceinline__ void block_argmin_lex(float& c, int& i, int tid,
                                                 float* swv, int* swi) {
#pragma unroll
  for (int off = 32; off; off >>= 1) {
    float c2 = __shfl_down(c, off, 64);
    int   i2 = __shfl_down(i, off, 64);
    if (c2 < c || (c2 == c && i2 < i)) { c = c2; i = i2; }
  }
  int wv = tid >> 6;
  if ((tid & 63) == 0) { swv[wv] = c; swi[wv] = i; }
  __syncthreads();
  float bc = swv[0]; int bi = swi[0];
#pragma unroll
  for (int w = 1; w < SELB / 64; w++) {
    float c2 = swv[w]; int i2 = swi[w];
    if (c2 < bc || (c2 == bc && i2 < bi)) { bc = c2; bi = i2; }
  }
  c = bc; i = bi;
  __syncthreads();
}

// K2: one block per (b,g). Reads cost row; recomputes iou from bbox.
// dyn_k from top-10 ious; pops dyn_k (cost,idx) mins = the matched anchors
// (stable rank < dyn_k). Sets bit g in mmask for each (ok) popped anchor.
__global__ __launch_bounds__(SELB) void k_sel(Params p) {
  __shared__ float swv[SELB / 64];
  __shared__ int   swi[SELB / 64];
  int bg = blockIdx.x;
  int b = bg / NG, g = bg % NG;
  int tid = threadIdx.x;

  const float* gt = p.lab + ((size_t)b * NG + g) * 5;
  float gx = gt[0], gy = gt[1], gw = gt[2], gh = gt[3];
  float glx = gx - 0.5f * gw, grx = gx + 0.5f * gw;
  float gty = gy - 0.5f * gh, gby = gy + 0.5f * gh;
  float area_g = gw * gh;

  const float*  crow = p.cost + (size_t)bg * NA;
  const float4* bb   = (const float4*)p.bbox + (size_t)b * NA;

  float v[10];                 // local top-10 ious, descending
  float cv[10]; int ci[10];    // local 10 smallest (cost, idx), ascending
#pragma unroll
  for (int j = 0; j < 10; j++) { v[j] = -1.0f; cv[j] = 3.4e38f; ci[j] = 0x7FFFFFFF; }

  for (int a = tid; a < NA; a += SELB) {
    float c = crow[a];
    float4 pb = bb[a];
    float iou = pair_iou(pb.x, pb.y, pb.z, pb.w, glx, gty, grx, gby, area_g);
    iou = (c < 5.0e8f) ? iou : 0.0f;   // !anchor_ok zeroing, via the 1e9 cost term

    if (iou > v[9]) {
      int j = 9;
      while (j > 0 && iou > v[j - 1]) { v[j] = v[j - 1]; j--; }
      v[j] = iou;
    }
    if (c < cv[9] || (c == cv[9] && a < ci[9])) {
      int j = 9;
      while (j > 0 && (c < cv[j - 1] || (c == cv[j - 1] && a < ci[j - 1]))) {
        cv[j] = cv[j - 1]; ci[j] = ci[j - 1]; j--;
      }
      cv[j] = c; ci[j] = a;
    }
  }

  // dyn_k = clamp(floor(sum top-10 ious), 1, ...)
  float sum = 0.0f; int ptr = 0;
  for (int it = 0; it < 10; it++) {
    float mv = (ptr < 10) ? v[ptr] : -1e30f;
    int   mi = tid;
    block_argmax(mv, mi, tid, swv, swi);
    if (tid == mi) ptr++;
    sum += mv;
  }
  int dynk = (int)sum;
  if (dynk < 1) dynk = 1;

  // pop dyn_k lexicographic (cost,idx) mins; each popped ok anchor is matched
  ptr = 0;
  unsigned* mrow = p.mmask + (size_t)b * NA;
  unsigned gbit = 1u << g;
  for (int it = 0; it < dynk; it++) {
    float mc = (ptr < 10) ? cv[ptr] : 3.4e38f;
    int   mi = (ptr < 10) ? ci[ptr] : 0x7FFFFFFF;
    block_argmin_lex(mc, mi, tid, swv, swi);
    if (ptr < 10 && ci[ptr] == mi) {       // unique owner
      if (mc < 5.0e8f) atomicOr(&mrow[mi], gbit);
      ptr++;
    }
  }
}

__device__ __forceinline__ float block_sum(float val, volatile float* sw) {
#pragma unroll
  for (int off = 32; off > 0; off >>= 1) val += __shfl_down(val, off, 64);
  int lane = threadIdx.x & 63, wv = threadIdx.x >> 6;
  __syncthreads();
  if (lane == 0) sw[wv] = val;
  __syncthreads();
  float r = 0.0f;
  if (threadIdx.x == 0) r = sw[0] + sw[1] + sw[2] + sw[3];
  return r;
}

// K3: per (b,a) dedup + loss contributions (no big matrix scans)
__global__ __launch_bounds__(256) void k_match(Params p) {
  __shared__ float sred[4];
  int b = blockIdx.y;
  int tid = threadIdx.x;
  int a = blockIdx.x * 256 + tid;
  bool valid = a < NA;

  float l_iou = 0.0f, l_obj = 0.0f, l_cls = 0.0f, l_nfg = 0.0f;
  bool fg = false; float pred_iou = 0.0f; int cg_ = 0;

  if (valid) {
    unsigned mask = p.mmask[b * NA + a];
    int am = __popc(mask);
    if (am > 1) {
      // argmin over the FULL cost column (all g, not just matched) — as reference
      const float* ccol = p.cost + (size_t)b * NG * NA + a;
      float cc[NG];
#pragma unroll
      for (int g = 0; g < NG; g++) cc[g] = ccol[(size_t)g * NA];
      float minc = 3.4e38f; int ming = 0;
#pragma unroll
      for (int g = 0; g < NG; g++) {
        if (cc[g] < minc) { minc = cc[g]; ming = g; }
      }
      mask = 1u << ming;
    }
    fg = (mask != 0u);

    float ol = p.objlog[b * NA + a];
    float tfg = fg ? 1.0f : 0.0f;
    l_obj = fmaxf(ol, 0.0f) - ol * tfg + __logf(1.0f + __expf(-fabsf(ol)));

    if (fg) {
      l_nfg = 1.0f;
      int mg = __ffs(mask) - 1;
      const float* gtm = p.lab + ((size_t)b * NG + mg) * 5;
      float gx = gtm[0], gy = gtm[1], gw = gtm[2], gh = gtm[3];
      cg_ = (int)gtm[4];
      float4 pb = ((const float4*)p.bbox)[(size_t)b * NA + a];
      // post-dedup there is exactly one matched gt: pred_iou == iou(a, mg),
      // and iou_elem(pred, reg_t) is the same value
      float iou = pair_iou(pb.x, pb.y, pb.z, pb.w,
                           gx - 0.5f * gw, gy - 0.5f * gh,
                           gx + 0.5f * gw, gy + 0.5f * gh, gw * gh);
      pred_iou = iou;
      l_iou = 1.0f - iou * iou;
    }
  }

  // wave-cooperative cls-loss for fg anchors: all 64 lanes split the 80 classes
  unsigned long long fgb = __ballot(fg);
  int lane = tid & 63;
  while (fgb) {
    int src = __ffsll(fgb) - 1;
    fgb &= fgb - 1ull;
    int   aa   = __shfl(a, src, 64);
    float piou = __shfl(pred_iou, src, 64);
    int   ccg  = __shfl(cg_, src, 64);

    int x, y, W, hw, lvl; float stride;
    anchor_geom(aa, x, y, W, hw, stride, lvl);
    const float* f = (lvl == 0) ? p.f8 : (lvl == 1) ? p.f16 : p.f32;
    const float* fb = f + (size_t)b * 85 * hw;
    int idx = y * W + x;

    float part = 0.0f;
#pragma unroll
    for (int c0 = 0; c0 < NC; c0 += 64) {
      int c = c0 + lane;
      if (c < NC) {
        float xl = fb[(size_t)(5 + c) * hw + idx];
        float t = (c == ccg) ? piou : 0.0f;
        part += fmaxf(xl, 0.0f) - xl * t + __logf(1.0f + __expf(-fabsf(xl)));
      }
    }
#pragma unroll
    for (int off = 32; off; off >>= 1) part += __shfl_down(part, off, 64);
    if (lane == 0) l_cls += part;
  }

  float s0 = block_sum(l_iou, sred);
  float s1 = block_sum(l_obj, sred);
  float s2 = block_sum(l_cls, sred);
  float s3 = block_sum(l_nfg, sred);
  if (tid == 0) {
    atomicAdd(&p.acc[0], s0);
    atomicAdd(&p.acc[1], s1);
    atomicAdd(&p.acc[2], s2);
    atomicAdd(&p.acc[3], s3);
  }
}

__global__ void k_final(Params p, float* out) {
  float li = p.acc[0], lo = p.acc[1], lc = p.acc[2], nf = p.acc[3];
  float nfg = fmaxf(nf, 1.0f);
  out[0] = (5.0f * li + 0.1f * lo + lc) / nfg;
}

extern "C" void kernel_launch(void* const* d_in, const int* in_sizes, int n_in,
                              void* d_out, int out_size, void* d_ws, size_t ws_size,
                              hipStream_t stream) {
  Params p;
  p.f8  = (const float*)d_in[0];
  p.f16 = (const float*)d_in[1];
  p.f32 = (const float*)d_in[2];
  p.lab = (const float*)d_in[3];

  float* w = (float*)d_ws;
  p.bbox   = w;              w += (size_t)NB * NA * 4;
  p.objlog = w;              w += (size_t)NB * NA;
  p.cost   = w;              w += (size_t)NB * NG * NA;
  p.mmask  = (unsigned*)w;   w += (size_t)NB * NA;
  p.acc    = w;              w += 4;

  // zero mmask + acc in one shot (they are adjacent)
  hipMemsetAsync(p.mmask, 0, ((size_t)NB * NA + 4) * sizeof(float), stream);

  dim3 gd((NA + 255) / 256, NB);
  k_cost<<<gd, 256, 0, stream>>>(p);
  k_sel<<<NB * NG, SELB, 0, stream>>>(p);
  k_match<<<gd, 256, 0, stream>>>(p);
  k_final<<<1, 1, 0, stream>>>(p, (float*)d_out);
}